// Round 5
// baseline (829.716 us; speedup 1.0000x reference)
//
#include <hip/hip_runtime.h>

constexpr int kB  = 512;
constexpr int kV  = 6890;
constexpr int kJ  = 24;
constexpr int kD  = kV * 3;   // 20670
constexpr int kNB = 10;
constexpr int kNF = 93;

// ---------------------------------------------------------------------------
// KA: batch-independent joint-regressor folding.
// JS[j][k][nb] = sum_v Jreg[j][v] * shapedirs[(v*3+k)*10+nb]
// JT[j][k]     = sum_v Jreg[j][v] * v_template[v*3+k]
// grid(72): one block per (j,k). block(256), wave butterfly + LDS reduce.
// ---------------------------------------------------------------------------
__global__ __launch_bounds__(256) void kA_js(
    const float* __restrict__ Jreg, const float* __restrict__ shapedirs,
    const float* __restrict__ v_template, float* __restrict__ js,
    float* __restrict__ jt) {
  int jk = blockIdx.x;
  int j = jk / 3, k = jk % 3;
  int tid = threadIdx.x;
  float acc[kNB];
  float accT = 0.f;
#pragma unroll
  for (int nb = 0; nb < kNB; ++nb) acc[nb] = 0.f;
  for (int v = tid; v < kV; v += 256) {
    float w = Jreg[(size_t)j * kV + v];
    const float* srow = shapedirs + (size_t)(v * 3 + k) * kNB;
    accT += w * v_template[v * 3 + k];
#pragma unroll
    for (int nb = 0; nb < kNB; ++nb) acc[nb] += w * srow[nb];
  }
#pragma unroll
  for (int nb = 0; nb < kNB; ++nb)
#pragma unroll
    for (int off = 32; off > 0; off >>= 1)
      acc[nb] += __shfl_down(acc[nb], off, 64);
#pragma unroll
  for (int off = 32; off > 0; off >>= 1) accT += __shfl_down(accT, off, 64);
  __shared__ float red[4][11];
  int wave = tid >> 6, lane = tid & 63;
  if (lane == 0) {
#pragma unroll
    for (int nb = 0; nb < kNB; ++nb) red[wave][nb] = acc[nb];
    red[wave][10] = accT;
  }
  __syncthreads();
  if (tid == 0) {
#pragma unroll
    for (int nb = 0; nb < kNB; ++nb)
      js[jk * kNB + nb] = red[0][nb] + red[1][nb] + red[2][nb] + red[3][nb];
    jt[jk] = red[0][10] + red[1][10] + red[2][10] + red[3][10];
  }
}

// ---------------------------------------------------------------------------
// KC: per-batch everything-small. Quat features -> pfT ([f][b] transposed),
// Rodrigues R (regs), Jp = JT + JS*betas (LDS), kinematic chain by tree
// level, G_skin, J_transformed. grid(kB), block(64) = 1 wave.
// ---------------------------------------------------------------------------
__global__ __launch_bounds__(64) void kC_batch(
    const float* __restrict__ pose, const float* __restrict__ betas,
    const float* __restrict__ trans, const float* __restrict__ js,
    const float* __restrict__ jt, float* __restrict__ pfT,
    float* __restrict__ Gskin, float* __restrict__ out_Jt) {
  const int parent[24] = {-1, 0, 0, 0, 1, 2, 3, 4, 5, 6, 7, 8,
                          9, 9, 9, 12, 13, 14, 16, 17, 18, 19, 20, 21};
  const int depth[24] = {0, 1, 1, 1, 2, 2, 2, 3, 3, 3, 4, 4,
                         4, 4, 4, 5, 5, 5, 6, 6, 7, 7, 8, 8};
  int b = blockIdx.x;
  int j = threadIdx.x;
  __shared__ float G[24][12];
  __shared__ float Jp_s[24][3];
  float R[9];
  if (j < 24) {
    float t0 = pose[b * 72 + 3 * j + 0];
    float t1 = pose[b * 72 + 3 * j + 1];
    float t2 = pose[b * 72 + 3 * j + 2];
    float a0 = t0 + 1e-8f, a1 = t1 + 1e-8f, a2 = t2 + 1e-8f;
    float angle = sqrtf(a0 * a0 + a1 * a1 + a2 * a2);
    float inv = 1.0f / angle;
    float h = 0.5f * angle;
    float c = cosf(h), s = sinf(h);
    float x = s * t0 * inv, y = s * t1 * inv, z = s * t2 * inv, w = c;
    if (j >= 1) {
      int f = 4 * (j - 1);
      pfT[(size_t)(f + 0) * kB + b] = x;
      pfT[(size_t)(f + 1) * kB + b] = y;
      pfT[(size_t)(f + 2) * kB + b] = z;
      pfT[(size_t)(f + 3) * kB + b] = c - 1.0f;
    } else {
      pfT[(size_t)92 * kB + b] = betas[b * kNB + 1];
    }
    float xx = x * x, yy = y * y, zz = z * z;
    float wx = w * x, wy = w * y, wz = w * z;
    float xy = x * y, xz = x * z, yz = y * z;
    R[0] = 1.f - 2.f * (yy + zz); R[1] = 2.f * (xy - wz); R[2] = 2.f * (xz + wy);
    R[3] = 2.f * (xy + wz); R[4] = 1.f - 2.f * (xx + zz); R[5] = 2.f * (yz - wx);
    R[6] = 2.f * (xz - wy); R[7] = 2.f * (yz + wx); R[8] = 1.f - 2.f * (xx + yy);
    float bet[kNB];
#pragma unroll
    for (int nb = 0; nb < kNB; ++nb) bet[nb] = betas[b * kNB + nb];
#pragma unroll
    for (int k = 0; k < 3; ++k) {
      float a = jt[j * 3 + k];
      const float* jr = js + (size_t)(j * 3 + k) * kNB;
#pragma unroll
      for (int nb = 0; nb < kNB; ++nb) a += jr[nb] * bet[nb];
      Jp_s[j][k] = a;
    }
  }
  __syncthreads();
  float tl[3];
  if (j < 24) {
    int p = parent[j];
#pragma unroll
    for (int k = 0; k < 3; ++k)
      tl[k] = (p >= 0) ? (Jp_s[j][k] - Jp_s[p][k]) : Jp_s[j][k];
    if (j == 0) {
#pragma unroll
      for (int r = 0; r < 3; ++r) {
        G[0][r * 4 + 0] = R[r * 3 + 0];
        G[0][r * 4 + 1] = R[r * 3 + 1];
        G[0][r * 4 + 2] = R[r * 3 + 2];
        G[0][r * 4 + 3] = tl[r];
      }
    }
  }
  __syncthreads();
  for (int lev = 1; lev <= 8; ++lev) {
    if (j < 24 && depth[j] == lev) {
      int p = parent[j];
      float nG[12];
#pragma unroll
      for (int r = 0; r < 3; ++r) {
        float g0 = G[p][r * 4 + 0], g1 = G[p][r * 4 + 1];
        float g2 = G[p][r * 4 + 2], g3 = G[p][r * 4 + 3];
        nG[r * 4 + 0] = g0 * R[0] + g1 * R[3] + g2 * R[6];
        nG[r * 4 + 1] = g0 * R[1] + g1 * R[4] + g2 * R[7];
        nG[r * 4 + 2] = g0 * R[2] + g1 * R[5] + g2 * R[8];
        nG[r * 4 + 3] = g0 * tl[0] + g1 * tl[1] + g2 * tl[2] + g3;
      }
#pragma unroll
      for (int e = 0; e < 12; ++e) G[j][e] = nG[e];
    }
    __syncthreads();
  }
  if (j < 24) {
    float tr[3];
#pragma unroll
    for (int k = 0; k < 3; ++k) tr[k] = trans[b * 3 + k];
#pragma unroll
    for (int k = 0; k < 3; ++k)
      out_Jt[b * 72 + j * 3 + k] = G[j][k * 4 + 3] + tr[k];
    float jp0 = Jp_s[j][0], jp1 = Jp_s[j][1], jp2 = Jp_s[j][2];
    float* gs = Gskin + b * 288 + j * 12;
#pragma unroll
    for (int r = 0; r < 3; ++r) {
      float t = G[j][r * 4 + 0] * jp0 + G[j][r * 4 + 1] * jp1 + G[j][r * 4 + 2] * jp2;
      gs[r * 4 + 0] = G[j][r * 4 + 0];
      gs[r * 4 + 1] = G[j][r * 4 + 1];
      gs[r * 4 + 2] = G[j][r * 4 + 2];
      gs[r * 4 + 3] = G[j][r * 4 + 3] - t;
    }
  }
}

// ---------------------------------------------------------------------------
// KF v2: fused blend + skin, HYBRID operand sourcing.
// Phase 1 (per-d): pd/sd register-resident; pfT and betas read as
//   WAVE-UNIFORM GLOBAL loads -> SGPRs (round-0 k14's proven codegen).
//   v_fmac v,s,v needs no VGPR temps, so the allocator has no pressure
//   incentive to evict pd[93].
// Phase 2 (wave kRow x 64 vertices): T = w . Gskin from LDS-staged Gskin;
//   vposed handed off through LDS (no 42 MB global round-trip).
// grid(108, 16), block(192) = 64 vertices = 192 d-rows. LDS ~16 KB.
// NOTES (hard-won, do not undo):
//  - NO min-waves clause in __launch_bounds__ (round 1: VGPR capped at 128,
//    pd spilled, 6.4 GB scratch).
//  - NO LDS staging of pfT/betas for phase 1 (rounds 2-4: ds_read results
//    are VGPR-only; the allocator reacted by spilling accs (r2, VGPR=256),
//    rematerializing pd loads (r3, VGPR=80, 279 MB FETCH), or spilling pd
//    despite asm pins (r4, 326 MB WRITE). SGPR operands sidestep all of it.
// ---------------------------------------------------------------------------
__global__ __launch_bounds__(192) void kF_blend_skin(
    const float* __restrict__ shapedirs, const float* __restrict__ posedirs,
    const float* __restrict__ v_template, const float* __restrict__ betas,
    const float* __restrict__ pfT, const float* __restrict__ weights,
    const float* __restrict__ Gskin, const float* __restrict__ trans,
    float* __restrict__ out_vshaped, float* __restrict__ out_vposed,
    float* __restrict__ out_v) {
  __shared__ __align__(16) float Gs_s[8 * 288];    // [t][j*12+r*4+e]
  __shared__ float vp_s[192][9];                   // [local d][t], pad 9

  const int tid = threadIdx.x;
  const int d0 = blockIdx.x * 192;
  const int v0 = blockIdx.x * 64;
  const int b0 = blockIdx.y * 32;
  const int d = d0 + tid;
  const bool act_d = d < kD;
  const int dl = act_d ? d : (kD - 1);
  const int kRow = tid >> 6;   // wave id = output row 0..2
  const int vloc = tid & 63;
  const bool act_v = (v0 + vloc) < kV;
  const int vl = act_v ? (v0 + vloc) : (kV - 1);

  // persistent per-thread data (amortized over 32 batches)
  float sd[kNB], pd[kNF], wreg[kJ];
#pragma unroll
  for (int k = 0; k < kNB; ++k) sd[k] = shapedirs[(size_t)dl * kNB + k];
#pragma unroll
  for (int f = 0; f < kNF; ++f) pd[f] = posedirs[(size_t)dl * kNF + f];
  float vt = v_template[dl];
#pragma unroll
  for (int j = 0; j < kJ; ++j) wreg[j] = weights[(size_t)vl * kJ + j];

#pragma unroll 1
  for (int bc = 0; bc < 4; ++bc) {
    // protects Gs_s/vp_s reuse from previous phase 2
    __syncthreads();

    const int bb = b0 + bc * 8;

    // stage Gskin for this 8-batch group
    {
      const float* src = Gskin + (size_t)bb * 288;
      for (int i = tid; i < 8 * 288; i += 192) Gs_s[i] = src[i];
    }

    // ---- phase 1: blend for 8 batches, this thread's d-row ----
    float ap_[8];
#pragma unroll
    for (int t = 0; t < 8; ++t) {
      const float* be = betas + (size_t)(bb + t) * kNB;  // wave-uniform -> SGPR
      float a = vt;
#pragma unroll
      for (int nb = 0; nb < kNB; ++nb) a += sd[nb] * be[nb];
      ap_[t] = a;
      if (act_d)
        out_vshaped[(size_t)(bb + t) * kD + d] = a;  // vshaped acc dies here
    }
#pragma unroll
    for (int f = 0; f < kNF; ++f) {
      float pdf = pd[f];
      const float* q = pfT + (size_t)f * kB + bb;  // wave-uniform -> SGPR
#pragma unroll
      for (int t = 0; t < 8; ++t) ap_[t] += pdf * q[t];
    }
#pragma unroll
    for (int t = 0; t < 8; ++t) {
      vp_s[tid][t] = ap_[t];
      if (act_d)
        out_vposed[(size_t)(bb + t) * kD + d] = ap_[t];
    }
    __syncthreads();

    // ---- phase 2: skin 8 batches, this thread = (row kRow, vertex vloc) ----
#pragma unroll 1
    for (int t = 0; t < 8; ++t) {
      int b = bb + t;
      const float4* Gt = (const float4*)(Gs_s + t * 288);
      float T0 = 0.f, T1 = 0.f, T2 = 0.f, T3 = 0.f;
#pragma unroll
      for (int j = 0; j < kJ; ++j) {
        float4 g = Gt[j * 3 + kRow];  // G[j], row kRow, 4 floats (broadcast)
        T0 += wreg[j] * g.x; T1 += wreg[j] * g.y;
        T2 += wreg[j] * g.z; T3 += wreg[j] * g.w;
      }
      float q0 = vp_s[vloc * 3 + 0][t];
      float q1 = vp_s[vloc * 3 + 1][t];
      float q2 = vp_s[vloc * 3 + 2][t];
      float val = T0 * q0 + T1 * q1 + T2 * q2 + T3 + trans[b * 3 + kRow];
      if (act_v)
        out_v[(size_t)b * kD + (size_t)(v0 + vloc) * 3 + kRow] = val;
    }
  }
}

// ---------------------------------------------------------------------------
extern "C" void kernel_launch(void* const* d_in, const int* in_sizes, int n_in,
                              void* d_out, int out_size, void* d_ws,
                              size_t ws_size, hipStream_t stream) {
  const float* pose       = (const float*)d_in[0];
  const float* betas      = (const float*)d_in[1];
  const float* trans      = (const float*)d_in[2];
  const float* v_template = (const float*)d_in[3];
  const float* shapedirs  = (const float*)d_in[4];
  const float* posedirs   = (const float*)d_in[5];
  const float* Jreg       = (const float*)d_in[6];
  const float* weights    = (const float*)d_in[7];

  float* out = (float*)d_out;
  float* out_v       = out;
  float* out_vposed  = out + (size_t)kB * kD;
  float* out_vshaped = out + 2 * (size_t)kB * kD;
  float* out_Jt      = out + 3 * (size_t)kB * kD;

  float* wsf   = (float*)d_ws;
  float* pfT   = wsf;                   // kNF*kB
  float* Gskin = pfT + kNF * kB;        // kB*288
  float* js    = Gskin + kB * 288;      // 72*10
  float* jt    = js + 72 * kNB;         // 72

  hipLaunchKernelGGL(kA_js, dim3(72), dim3(256), 0, stream, Jreg, shapedirs,
                     v_template, js, jt);
  hipLaunchKernelGGL(kC_batch, dim3(kB), dim3(64), 0, stream, pose, betas,
                     trans, js, jt, pfT, Gskin, out_Jt);
  hipLaunchKernelGGL(kF_blend_skin, dim3(108, 16), dim3(192), 0, stream,
                     shapedirs, posedirs, v_template, betas, pfT, weights,
                     Gskin, trans, out_vshaped, out_vposed, out_v);
}

// Round 6
// 287.135 us; speedup vs baseline: 2.8896x; 2.8896x over previous
//
#include <hip/hip_runtime.h>

constexpr int kB  = 512;
constexpr int kV  = 6890;
constexpr int kJ  = 24;
constexpr int kD  = kV * 3;   // 20670
constexpr int kNB = 10;
constexpr int kNF = 93;

// ---------------------------------------------------------------------------
// KA: batch-independent joint-regressor folding, v-split x4 + atomicAdd.
// JS[j][k][nb] = sum_v Jreg[j][v] * shapedirs[(v*3+k)*10+nb]
// JT[j][k]     = sum_v Jreg[j][v] * v_template[v*3+k]
// grid(72,4): blockIdx.x = (j,k), blockIdx.y = v-partition. block(256).
// js/jt zeroed by hipMemsetAsync before launch; 11 atomicAdds per block.
// (72 blocks = 28% CU fill + 27 serial iters was latency-bound; 288 blocks
//  at 7 iters quadruples parallelism.)
// ---------------------------------------------------------------------------
__global__ __launch_bounds__(256) void kA_js(
    const float* __restrict__ Jreg, const float* __restrict__ shapedirs,
    const float* __restrict__ v_template, float* __restrict__ js,
    float* __restrict__ jt) {
  int jk = blockIdx.x;
  int j = jk / 3, k = jk % 3;
  int tid = threadIdx.x;
  float acc[kNB];
  float accT = 0.f;
#pragma unroll
  for (int nb = 0; nb < kNB; ++nb) acc[nb] = 0.f;
  for (int v = blockIdx.y * 256 + tid; v < kV; v += 1024) {
    float w = Jreg[(size_t)j * kV + v];
    const float* srow = shapedirs + (size_t)(v * 3 + k) * kNB;
    accT += w * v_template[v * 3 + k];
#pragma unroll
    for (int nb = 0; nb < kNB; ++nb) acc[nb] += w * srow[nb];
  }
#pragma unroll
  for (int nb = 0; nb < kNB; ++nb)
#pragma unroll
    for (int off = 32; off > 0; off >>= 1)
      acc[nb] += __shfl_down(acc[nb], off, 64);
#pragma unroll
  for (int off = 32; off > 0; off >>= 1) accT += __shfl_down(accT, off, 64);
  __shared__ float red[4][11];
  int wave = tid >> 6, lane = tid & 63;
  if (lane == 0) {
#pragma unroll
    for (int nb = 0; nb < kNB; ++nb) red[wave][nb] = acc[nb];
    red[wave][10] = accT;
  }
  __syncthreads();
  if (tid == 0) {
#pragma unroll
    for (int nb = 0; nb < kNB; ++nb)
      atomicAdd(&js[jk * kNB + nb],
                red[0][nb] + red[1][nb] + red[2][nb] + red[3][nb]);
    atomicAdd(&jt[jk], red[0][10] + red[1][10] + red[2][10] + red[3][10]);
  }
}

// ---------------------------------------------------------------------------
// KC: per-batch everything-small. Quat features -> pfT ([f][b] transposed),
// Rodrigues R (regs), Jp = JT + JS*betas (LDS), kinematic chain by tree
// level, G_skin, J_transformed. grid(kB), block(64) = 1 wave.
// ---------------------------------------------------------------------------
__global__ __launch_bounds__(64) void kC_batch(
    const float* __restrict__ pose, const float* __restrict__ betas,
    const float* __restrict__ trans, const float* __restrict__ js,
    const float* __restrict__ jt, float* __restrict__ pfT,
    float* __restrict__ Gskin, float* __restrict__ out_Jt) {
  const int parent[24] = {-1, 0, 0, 0, 1, 2, 3, 4, 5, 6, 7, 8,
                          9, 9, 9, 12, 13, 14, 16, 17, 18, 19, 20, 21};
  const int depth[24] = {0, 1, 1, 1, 2, 2, 2, 3, 3, 3, 4, 4,
                         4, 4, 4, 5, 5, 5, 6, 6, 7, 7, 8, 8};
  int b = blockIdx.x;
  int j = threadIdx.x;
  __shared__ float G[24][12];
  __shared__ float Jp_s[24][3];
  float R[9];
  if (j < 24) {
    float t0 = pose[b * 72 + 3 * j + 0];
    float t1 = pose[b * 72 + 3 * j + 1];
    float t2 = pose[b * 72 + 3 * j + 2];
    float a0 = t0 + 1e-8f, a1 = t1 + 1e-8f, a2 = t2 + 1e-8f;
    float angle = sqrtf(a0 * a0 + a1 * a1 + a2 * a2);
    float inv = 1.0f / angle;
    float h = 0.5f * angle;
    float c = cosf(h), s = sinf(h);
    float x = s * t0 * inv, y = s * t1 * inv, z = s * t2 * inv, w = c;
    if (j >= 1) {
      int f = 4 * (j - 1);
      pfT[(size_t)(f + 0) * kB + b] = x;
      pfT[(size_t)(f + 1) * kB + b] = y;
      pfT[(size_t)(f + 2) * kB + b] = z;
      pfT[(size_t)(f + 3) * kB + b] = c - 1.0f;
    } else {
      pfT[(size_t)92 * kB + b] = betas[b * kNB + 1];
    }
    float xx = x * x, yy = y * y, zz = z * z;
    float wx = w * x, wy = w * y, wz = w * z;
    float xy = x * y, xz = x * z, yz = y * z;
    R[0] = 1.f - 2.f * (yy + zz); R[1] = 2.f * (xy - wz); R[2] = 2.f * (xz + wy);
    R[3] = 2.f * (xy + wz); R[4] = 1.f - 2.f * (xx + zz); R[5] = 2.f * (yz - wx);
    R[6] = 2.f * (xz - wy); R[7] = 2.f * (yz + wx); R[8] = 1.f - 2.f * (xx + yy);
    float bet[kNB];
#pragma unroll
    for (int nb = 0; nb < kNB; ++nb) bet[nb] = betas[b * kNB + nb];
#pragma unroll
    for (int k = 0; k < 3; ++k) {
      float a = jt[j * 3 + k];
      const float* jr = js + (size_t)(j * 3 + k) * kNB;
#pragma unroll
      for (int nb = 0; nb < kNB; ++nb) a += jr[nb] * bet[nb];
      Jp_s[j][k] = a;
    }
  }
  __syncthreads();
  float tl[3];
  if (j < 24) {
    int p = parent[j];
#pragma unroll
    for (int k = 0; k < 3; ++k)
      tl[k] = (p >= 0) ? (Jp_s[j][k] - Jp_s[p][k]) : Jp_s[j][k];
    if (j == 0) {
#pragma unroll
      for (int r = 0; r < 3; ++r) {
        G[0][r * 4 + 0] = R[r * 3 + 0];
        G[0][r * 4 + 1] = R[r * 3 + 1];
        G[0][r * 4 + 2] = R[r * 3 + 2];
        G[0][r * 4 + 3] = tl[r];
      }
    }
  }
  __syncthreads();
  for (int lev = 1; lev <= 8; ++lev) {
    if (j < 24 && depth[j] == lev) {
      int p = parent[j];
      float nG[12];
#pragma unroll
      for (int r = 0; r < 3; ++r) {
        float g0 = G[p][r * 4 + 0], g1 = G[p][r * 4 + 1];
        float g2 = G[p][r * 4 + 2], g3 = G[p][r * 4 + 3];
        nG[r * 4 + 0] = g0 * R[0] + g1 * R[3] + g2 * R[6];
        nG[r * 4 + 1] = g0 * R[1] + g1 * R[4] + g2 * R[7];
        nG[r * 4 + 2] = g0 * R[2] + g1 * R[5] + g2 * R[8];
        nG[r * 4 + 3] = g0 * tl[0] + g1 * tl[1] + g2 * tl[2] + g3;
      }
#pragma unroll
      for (int e = 0; e < 12; ++e) G[j][e] = nG[e];
    }
    __syncthreads();
  }
  if (j < 24) {
    float tr[3];
#pragma unroll
    for (int k = 0; k < 3; ++k) tr[k] = trans[b * 3 + k];
#pragma unroll
    for (int k = 0; k < 3; ++k)
      out_Jt[b * 72 + j * 3 + k] = G[j][k * 4 + 3] + tr[k];
    float jp0 = Jp_s[j][0], jp1 = Jp_s[j][1], jp2 = Jp_s[j][2];
    float* gs = Gskin + b * 288 + j * 12;
#pragma unroll
    for (int r = 0; r < 3; ++r) {
      float t = G[j][r * 4 + 0] * jp0 + G[j][r * 4 + 1] * jp1 + G[j][r * 4 + 2] * jp2;
      gs[r * 4 + 0] = G[j][r * 4 + 0];
      gs[r * 4 + 1] = G[j][r * 4 + 1];
      gs[r * 4 + 2] = G[j][r * 4 + 2];
      gs[r * 4 + 3] = G[j][r * 4 + 3] - t;
    }
  }
}

// ---------------------------------------------------------------------------
// K14: fused shape+pose blend (r0-proven structure, batch tile 16).
// Thread owns one d-row; dirs rows in registers; wave-uniform scalar loads
// of betas/pfT (-> SGPRs, the only operand sourcing that never triggered
// spill/remat across rounds 1-5). BT=16 doubles FMAs per scalar-load wait.
// vshaped stored immediately so its accumulators die before the f-loop.
// grid(81, 16), block(256).
// ---------------------------------------------------------------------------
__global__ __launch_bounds__(256) void k14_fused(
    const float* __restrict__ shapedirs, const float* __restrict__ posedirs,
    const float* __restrict__ v_template, const float* __restrict__ betas,
    const float* __restrict__ pfT, float* __restrict__ out_vshaped,
    float* __restrict__ out_vposed) {
  int tid = threadIdx.x;
  int d = blockIdx.x * 256 + tid;
  bool active = d < kD;
  int dl = active ? d : (kD - 1);  // clamp for loads
  float sd[kNB], pd[kNF];
#pragma unroll
  for (int k = 0; k < kNB; ++k) sd[k] = shapedirs[(size_t)dl * kNB + k];
#pragma unroll
  for (int f = 0; f < kNF; ++f) pd[f] = posedirs[(size_t)dl * kNF + f];
  float vt = v_template[dl];
  int b0 = blockIdx.y * 32;
#pragma unroll 1
  for (int bc = 0; bc < 2; ++bc) {
    int bb = b0 + bc * 16;
    float ap[16];
#pragma unroll
    for (int t = 0; t < 16; ++t) {
      const float* be = betas + (size_t)(bb + t) * kNB;  // wave-uniform
      float a = vt;
#pragma unroll
      for (int k = 0; k < kNB; ++k) a += sd[k] * be[k];
      ap[t] = a;
      if (active) out_vshaped[(size_t)(bb + t) * kD + d] = a;
    }
#pragma unroll
    for (int f = 0; f < kNF; ++f) {
      float pdf = pd[f];
      const float* q = pfT + (size_t)f * kB + bb;  // wave-uniform, 64B-aligned
#pragma unroll
      for (int t = 0; t < 16; ++t) ap[t] += pdf * q[t];
    }
    if (active) {
#pragma unroll
      for (int t = 0; t < 16; ++t)
        out_vposed[(size_t)(bb + t) * kD + d] = ap[t];
    }
  }
}

// ---------------------------------------------------------------------------
// K5: LBS skinning (r0-proven structure, batch pairs for 2x MLP).
// Block owns a 256-vertex tile; weights row in registers; per pair of
// batches two independent wave-uniform Gskin scalar-load streams feed
// interleaved TA/TB accumulators.
// grid(27, 64), block(256)
// ---------------------------------------------------------------------------
__global__ __launch_bounds__(256) void k5_skin(
    const float* __restrict__ weights, const float* __restrict__ Gskin,
    const float* __restrict__ trans, const float* __restrict__ vposed,
    float* __restrict__ out_v) {
  int tid = threadIdx.x;
  int v = blockIdx.x * 256 + tid;
  bool active = v < kV;
  int vl = active ? v : (kV - 1);
  float w[kJ];
#pragma unroll
  for (int j = 0; j < kJ; ++j) w[j] = weights[(size_t)vl * kJ + j];
  int b0 = blockIdx.y * 8;
#pragma unroll 1
  for (int bp = 0; bp < 4; ++bp) {
    int bA = b0 + bp * 2;
    int bBt = bA + 1;
    const float* GA = Gskin + (size_t)bA * 288;   // wave-uniform
    const float* GB = Gskin + (size_t)bBt * 288;  // wave-uniform
    float TA[12], TB[12];
#pragma unroll
    for (int e = 0; e < 12; ++e) { TA[e] = 0.f; TB[e] = 0.f; }
#pragma unroll
    for (int j = 0; j < kJ; ++j) {
      float wj = w[j];
#pragma unroll
      for (int e = 0; e < 12; ++e) {
        TA[e] += wj * GA[j * 12 + e];
        TB[e] += wj * GB[j * 12 + e];
      }
    }
    float trA0 = trans[bA * 3 + 0], trA1 = trans[bA * 3 + 1], trA2 = trans[bA * 3 + 2];
    float trB0 = trans[bBt * 3 + 0], trB1 = trans[bBt * 3 + 1], trB2 = trans[bBt * 3 + 2];
    size_t baseA = (size_t)bA * kD + (size_t)vl * 3;
    size_t baseB = (size_t)bBt * kD + (size_t)vl * 3;
    float a0 = vposed[baseA + 0], a1 = vposed[baseA + 1], a2 = vposed[baseA + 2];
    float b0v = vposed[baseB + 0], b1v = vposed[baseB + 1], b2v = vposed[baseB + 2];
    if (active) {
      out_v[baseA + 0] = TA[0] * a0 + TA[1] * a1 + TA[2] * a2 + TA[3] + trA0;
      out_v[baseA + 1] = TA[4] * a0 + TA[5] * a1 + TA[6] * a2 + TA[7] + trA1;
      out_v[baseA + 2] = TA[8] * a0 + TA[9] * a1 + TA[10] * a2 + TA[11] + trA2;
      out_v[baseB + 0] = TB[0] * b0v + TB[1] * b1v + TB[2] * b2v + TB[3] + trB0;
      out_v[baseB + 1] = TB[4] * b0v + TB[5] * b1v + TB[6] * b2v + TB[7] + trB1;
      out_v[baseB + 2] = TB[8] * b0v + TB[9] * b1v + TB[10] * b2v + TB[11] + trB2;
    }
  }
}

// ---------------------------------------------------------------------------
extern "C" void kernel_launch(void* const* d_in, const int* in_sizes, int n_in,
                              void* d_out, int out_size, void* d_ws,
                              size_t ws_size, hipStream_t stream) {
  const float* pose       = (const float*)d_in[0];
  const float* betas      = (const float*)d_in[1];
  const float* trans      = (const float*)d_in[2];
  const float* v_template = (const float*)d_in[3];
  const float* shapedirs  = (const float*)d_in[4];
  const float* posedirs   = (const float*)d_in[5];
  const float* Jreg       = (const float*)d_in[6];
  const float* weights    = (const float*)d_in[7];

  float* out = (float*)d_out;
  float* out_v       = out;
  float* out_vposed  = out + (size_t)kB * kD;
  float* out_vshaped = out + 2 * (size_t)kB * kD;
  float* out_Jt      = out + 3 * (size_t)kB * kD;

  float* wsf   = (float*)d_ws;
  float* pfT   = wsf;                   // kNF*kB
  float* Gskin = pfT + kNF * kB;        // kB*288
  float* js    = Gskin + kB * 288;      // 72*10
  float* jt    = js + 72 * kNB;         // 72

  // zero the atomic accumulators (js: 720 floats, jt: 72 floats, contiguous)
  hipMemsetAsync(js, 0, (72 * kNB + 72) * sizeof(float), stream);

  hipLaunchKernelGGL(kA_js, dim3(72, 4), dim3(256), 0, stream, Jreg, shapedirs,
                     v_template, js, jt);
  hipLaunchKernelGGL(kC_batch, dim3(kB), dim3(64), 0, stream, pose, betas,
                     trans, js, jt, pfT, Gskin, out_Jt);
  hipLaunchKernelGGL(k14_fused, dim3((kD + 255) / 256, 16), dim3(256), 0,
                     stream, shapedirs, posedirs, v_template, betas, pfT,
                     out_vshaped, out_vposed);
  hipLaunchKernelGGL(k5_skin, dim3((kV + 255) / 256, 64), dim3(256), 0, stream,
                     weights, Gskin, trans, out_vposed, out_v);
}

// Round 7
// 252.222 us; speedup vs baseline: 3.2896x; 1.1384x over previous
//
#include <hip/hip_runtime.h>

constexpr int kB  = 512;
constexpr int kV  = 6890;
constexpr int kJ  = 24;
constexpr int kD  = kV * 3;   // 20670
constexpr int kNB = 10;
constexpr int kNF = 93;

// ---------------------------------------------------------------------------
// KA: batch-independent joint-regressor folding, v-split x4 + atomicAdd.
// grid(72,4): blockIdx.x = (j,k), blockIdx.y = v-partition. block(256).
// js/jt zeroed by hipMemsetAsync before launch.
// ---------------------------------------------------------------------------
__global__ __launch_bounds__(256) void kA_js(
    const float* __restrict__ Jreg, const float* __restrict__ shapedirs,
    const float* __restrict__ v_template, float* __restrict__ js,
    float* __restrict__ jt) {
  int jk = blockIdx.x;
  int j = jk / 3, k = jk % 3;
  int tid = threadIdx.x;
  float acc[kNB];
  float accT = 0.f;
#pragma unroll
  for (int nb = 0; nb < kNB; ++nb) acc[nb] = 0.f;
  for (int v = blockIdx.y * 256 + tid; v < kV; v += 1024) {
    float w = Jreg[(size_t)j * kV + v];
    const float* srow = shapedirs + (size_t)(v * 3 + k) * kNB;
    accT += w * v_template[v * 3 + k];
#pragma unroll
    for (int nb = 0; nb < kNB; ++nb) acc[nb] += w * srow[nb];
  }
#pragma unroll
  for (int nb = 0; nb < kNB; ++nb)
#pragma unroll
    for (int off = 32; off > 0; off >>= 1)
      acc[nb] += __shfl_down(acc[nb], off, 64);
#pragma unroll
  for (int off = 32; off > 0; off >>= 1) accT += __shfl_down(accT, off, 64);
  __shared__ float red[4][11];
  int wave = tid >> 6, lane = tid & 63;
  if (lane == 0) {
#pragma unroll
    for (int nb = 0; nb < kNB; ++nb) red[wave][nb] = acc[nb];
    red[wave][10] = accT;
  }
  __syncthreads();
  if (tid == 0) {
#pragma unroll
    for (int nb = 0; nb < kNB; ++nb)
      atomicAdd(&js[jk * kNB + nb],
                red[0][nb] + red[1][nb] + red[2][nb] + red[3][nb]);
    atomicAdd(&jt[jk], red[0][10] + red[1][10] + red[2][10] + red[3][10]);
  }
}

// ---------------------------------------------------------------------------
// KC: per-batch everything-small. Quat features -> pfT ([f][b] transposed),
// Rodrigues R (regs), Jp = JT + JS*betas (LDS), kinematic chain by tree
// level, G_skin, J_transformed. grid(kB), block(64) = 1 wave.
// ---------------------------------------------------------------------------
__global__ __launch_bounds__(64) void kC_batch(
    const float* __restrict__ pose, const float* __restrict__ betas,
    const float* __restrict__ trans, const float* __restrict__ js,
    const float* __restrict__ jt, float* __restrict__ pfT,
    float* __restrict__ Gskin, float* __restrict__ out_Jt) {
  const int parent[24] = {-1, 0, 0, 0, 1, 2, 3, 4, 5, 6, 7, 8,
                          9, 9, 9, 12, 13, 14, 16, 17, 18, 19, 20, 21};
  const int depth[24] = {0, 1, 1, 1, 2, 2, 2, 3, 3, 3, 4, 4,
                         4, 4, 4, 5, 5, 5, 6, 6, 7, 7, 8, 8};
  int b = blockIdx.x;
  int j = threadIdx.x;
  __shared__ float G[24][12];
  __shared__ float Jp_s[24][3];
  float R[9];
  if (j < 24) {
    float t0 = pose[b * 72 + 3 * j + 0];
    float t1 = pose[b * 72 + 3 * j + 1];
    float t2 = pose[b * 72 + 3 * j + 2];
    float a0 = t0 + 1e-8f, a1 = t1 + 1e-8f, a2 = t2 + 1e-8f;
    float angle = sqrtf(a0 * a0 + a1 * a1 + a2 * a2);
    float inv = 1.0f / angle;
    float h = 0.5f * angle;
    float c = cosf(h), s = sinf(h);
    float x = s * t0 * inv, y = s * t1 * inv, z = s * t2 * inv, w = c;
    if (j >= 1) {
      int f = 4 * (j - 1);
      pfT[(size_t)(f + 0) * kB + b] = x;
      pfT[(size_t)(f + 1) * kB + b] = y;
      pfT[(size_t)(f + 2) * kB + b] = z;
      pfT[(size_t)(f + 3) * kB + b] = c - 1.0f;
    } else {
      pfT[(size_t)92 * kB + b] = betas[b * kNB + 1];
    }
    float xx = x * x, yy = y * y, zz = z * z;
    float wx = w * x, wy = w * y, wz = w * z;
    float xy = x * y, xz = x * z, yz = y * z;
    R[0] = 1.f - 2.f * (yy + zz); R[1] = 2.f * (xy - wz); R[2] = 2.f * (xz + wy);
    R[3] = 2.f * (xy + wz); R[4] = 1.f - 2.f * (xx + zz); R[5] = 2.f * (yz - wx);
    R[6] = 2.f * (xz - wy); R[7] = 2.f * (yz + wx); R[8] = 1.f - 2.f * (xx + yy);
    float bet[kNB];
#pragma unroll
    for (int nb = 0; nb < kNB; ++nb) bet[nb] = betas[b * kNB + nb];
#pragma unroll
    for (int k = 0; k < 3; ++k) {
      float a = jt[j * 3 + k];
      const float* jr = js + (size_t)(j * 3 + k) * kNB;
#pragma unroll
      for (int nb = 0; nb < kNB; ++nb) a += jr[nb] * bet[nb];
      Jp_s[j][k] = a;
    }
  }
  __syncthreads();
  float tl[3];
  if (j < 24) {
    int p = parent[j];
#pragma unroll
    for (int k = 0; k < 3; ++k)
      tl[k] = (p >= 0) ? (Jp_s[j][k] - Jp_s[p][k]) : Jp_s[j][k];
    if (j == 0) {
#pragma unroll
      for (int r = 0; r < 3; ++r) {
        G[0][r * 4 + 0] = R[r * 3 + 0];
        G[0][r * 4 + 1] = R[r * 3 + 1];
        G[0][r * 4 + 2] = R[r * 3 + 2];
        G[0][r * 4 + 3] = tl[r];
      }
    }
  }
  __syncthreads();
  for (int lev = 1; lev <= 8; ++lev) {
    if (j < 24 && depth[j] == lev) {
      int p = parent[j];
      float nG[12];
#pragma unroll
      for (int r = 0; r < 3; ++r) {
        float g0 = G[p][r * 4 + 0], g1 = G[p][r * 4 + 1];
        float g2 = G[p][r * 4 + 2], g3 = G[p][r * 4 + 3];
        nG[r * 4 + 0] = g0 * R[0] + g1 * R[3] + g2 * R[6];
        nG[r * 4 + 1] = g0 * R[1] + g1 * R[4] + g2 * R[7];
        nG[r * 4 + 2] = g0 * R[2] + g1 * R[5] + g2 * R[8];
        nG[r * 4 + 3] = g0 * tl[0] + g1 * tl[1] + g2 * tl[2] + g3;
      }
#pragma unroll
      for (int e = 0; e < 12; ++e) G[j][e] = nG[e];
    }
    __syncthreads();
  }
  if (j < 24) {
    float tr[3];
#pragma unroll
    for (int k = 0; k < 3; ++k) tr[k] = trans[b * 3 + k];
#pragma unroll
    for (int k = 0; k < 3; ++k)
      out_Jt[b * 72 + j * 3 + k] = G[j][k * 4 + 3] + tr[k];
    float jp0 = Jp_s[j][0], jp1 = Jp_s[j][1], jp2 = Jp_s[j][2];
    float* gs = Gskin + b * 288 + j * 12;
#pragma unroll
    for (int r = 0; r < 3; ++r) {
      float t = G[j][r * 4 + 0] * jp0 + G[j][r * 4 + 1] * jp1 + G[j][r * 4 + 2] * jp2;
      gs[r * 4 + 0] = G[j][r * 4 + 0];
      gs[r * 4 + 1] = G[j][r * 4 + 1];
      gs[r * 4 + 2] = G[j][r * 4 + 2];
      gs[r * 4 + 3] = G[j][r * 4 + 3] - t;
    }
  }
}

// ---------------------------------------------------------------------------
// K14: fused shape+pose blend — EXACT r0-proven form (BT=8, 4 bc groups).
// Thread owns one d-row; dirs rows in registers; wave-uniform scalar loads
// of betas/pfT -> SGPRs (only operand sourcing that never triggered
// spill/remat across rounds 1-5). grid(81, 16), block(256).
// ---------------------------------------------------------------------------
__global__ __launch_bounds__(256) void k14_fused(
    const float* __restrict__ shapedirs, const float* __restrict__ posedirs,
    const float* __restrict__ v_template, const float* __restrict__ betas,
    const float* __restrict__ pfT, float* __restrict__ out_vshaped,
    float* __restrict__ out_vposed) {
  int tid = threadIdx.x;
  int d = blockIdx.x * 256 + tid;
  bool active = d < kD;
  int dl = active ? d : (kD - 1);  // clamp for loads
  float sd[kNB], pd[kNF];
#pragma unroll
  for (int k = 0; k < kNB; ++k) sd[k] = shapedirs[(size_t)dl * kNB + k];
#pragma unroll
  for (int f = 0; f < kNF; ++f) pd[f] = posedirs[(size_t)dl * kNF + f];
  float vt = v_template[dl];
  int b0 = blockIdx.y * 32;
#pragma unroll 1
  for (int bc = 0; bc < 4; ++bc) {
    int bb = b0 + bc * 8;
    float as[8], ap[8];
#pragma unroll
    for (int t = 0; t < 8; ++t) {
      const float* be = betas + (size_t)(bb + t) * kNB;  // wave-uniform
      float a = vt;
#pragma unroll
      for (int k = 0; k < kNB; ++k) a += sd[k] * be[k];
      as[t] = a;
      ap[t] = a;
    }
#pragma unroll
    for (int f = 0; f < kNF; ++f) {
      float pdf = pd[f];
      const float* q = pfT + (size_t)f * kB + bb;  // wave-uniform
#pragma unroll
      for (int t = 0; t < 8; ++t) ap[t] += pdf * q[t];
    }
    if (active) {
#pragma unroll
      for (int t = 0; t < 8; ++t) {
        size_t idx = (size_t)(bb + t) * kD + d;
        out_vshaped[idx] = as[t];
        out_vposed[idx] = ap[t];
      }
    }
  }
}

// ---------------------------------------------------------------------------
// K5 v3: LBS skinning with LDS-staged Gskin.
// The r0/r6 scalar-path j-loop serialized on s_load latency (576 dwords per
// batch-pair through ~112 SGPRs -> [s_load batch, lgkmcnt wait, FMA burst]
// repeated; 37% VALUBusy, 63% stall, 77 us). Now: 8 batches of Gskin
// (9.2 KB) staged coalesced into LDS once per block; j-loop feeds from
// ds_read_b128 broadcasts (uniform addr, conflict-free, compiler pipelines
// lgkmcnt fine-grained). Live set ~60 floats -> no allocator pathology
// (r2-r4's required ~130). #pragma unroll 4 caps the ds_read hoist window.
// vposed prefetched before the j-loop so global latency hides under FMAs.
// grid(27, 64), block(256).
// ---------------------------------------------------------------------------
__global__ __launch_bounds__(256) void k5_skin(
    const float* __restrict__ weights, const float* __restrict__ Gskin,
    const float* __restrict__ trans, const float* __restrict__ vposed,
    float* __restrict__ out_v) {
  __shared__ __align__(16) float Gs[8 * 288];  // 9216 B
  int tid = threadIdx.x;
  int v = blockIdx.x * 256 + tid;
  bool active = v < kV;
  int vl = active ? v : (kV - 1);
  float w[kJ];
#pragma unroll
  for (int j = 0; j < kJ; ++j) w[j] = weights[(size_t)vl * kJ + j];
  int b0 = blockIdx.y * 8;
  // stage 8 batches of Gskin, coalesced
  {
    const float* src = Gskin + (size_t)b0 * 288;
#pragma unroll
    for (int i = 0; i < 9; ++i) Gs[i * 256 + tid] = src[i * 256 + tid];
  }
  __syncthreads();
#pragma unroll 1
  for (int bi = 0; bi < 8; ++bi) {
    int b = b0 + bi;
    // prefetch vposed early; latency hides under the j-loop
    size_t base = (size_t)b * kD + (size_t)vl * 3;
    float q0 = vposed[base + 0];
    float q1 = vposed[base + 1];
    float q2 = vposed[base + 2];
    float tr0 = trans[b * 3 + 0];
    float tr1 = trans[b * 3 + 1];
    float tr2 = trans[b * 3 + 2];
    const float4* Gt = (const float4*)(Gs + bi * 288);
    float T0 = 0.f, T1 = 0.f, T2 = 0.f, T3 = 0.f;
    float T4 = 0.f, T5 = 0.f, T6 = 0.f, T7 = 0.f;
    float T8 = 0.f, T9 = 0.f, T10 = 0.f, T11 = 0.f;
#pragma unroll 4
    for (int j = 0; j < kJ; ++j) {
      float wj = w[j];
      float4 ga = Gt[j * 3 + 0];  // broadcast ds_read_b128
      float4 gb = Gt[j * 3 + 1];
      float4 gc = Gt[j * 3 + 2];
      T0 += wj * ga.x; T1 += wj * ga.y; T2 += wj * ga.z; T3 += wj * ga.w;
      T4 += wj * gb.x; T5 += wj * gb.y; T6 += wj * gb.z; T7 += wj * gb.w;
      T8 += wj * gc.x; T9 += wj * gc.y; T10 += wj * gc.z; T11 += wj * gc.w;
    }
    if (active) {
      out_v[base + 0] = T0 * q0 + T1 * q1 + T2 * q2 + T3 + tr0;
      out_v[base + 1] = T4 * q0 + T5 * q1 + T6 * q2 + T7 + tr1;
      out_v[base + 2] = T8 * q0 + T9 * q1 + T10 * q2 + T11 + tr2;
    }
  }
}

// ---------------------------------------------------------------------------
extern "C" void kernel_launch(void* const* d_in, const int* in_sizes, int n_in,
                              void* d_out, int out_size, void* d_ws,
                              size_t ws_size, hipStream_t stream) {
  const float* pose       = (const float*)d_in[0];
  const float* betas      = (const float*)d_in[1];
  const float* trans      = (const float*)d_in[2];
  const float* v_template = (const float*)d_in[3];
  const float* shapedirs  = (const float*)d_in[4];
  const float* posedirs   = (const float*)d_in[5];
  const float* Jreg       = (const float*)d_in[6];
  const float* weights    = (const float*)d_in[7];

  float* out = (float*)d_out;
  float* out_v       = out;
  float* out_vposed  = out + (size_t)kB * kD;
  float* out_vshaped = out + 2 * (size_t)kB * kD;
  float* out_Jt      = out + 3 * (size_t)kB * kD;

  float* wsf   = (float*)d_ws;
  float* pfT   = wsf;                   // kNF*kB
  float* Gskin = pfT + kNF * kB;        // kB*288
  float* js    = Gskin + kB * 288;      // 72*10
  float* jt    = js + 72 * kNB;         // 72

  // zero the atomic accumulators (js: 720 floats, jt: 72 floats, contiguous)
  hipMemsetAsync(js, 0, (72 * kNB + 72) * sizeof(float), stream);

  hipLaunchKernelGGL(kA_js, dim3(72, 4), dim3(256), 0, stream, Jreg, shapedirs,
                     v_template, js, jt);
  hipLaunchKernelGGL(kC_batch, dim3(kB), dim3(64), 0, stream, pose, betas,
                     trans, js, jt, pfT, Gskin, out_Jt);
  hipLaunchKernelGGL(k14_fused, dim3((kD + 255) / 256, 16), dim3(256), 0,
                     stream, shapedirs, posedirs, v_template, betas, pfT,
                     out_vshaped, out_vposed);
  hipLaunchKernelGGL(k5_skin, dim3((kV + 255) / 256, 64), dim3(256), 0, stream,
                     weights, Gskin, trans, out_vposed, out_v);
}